// Round 1
// baseline (1740.751 us; speedup 1.0000x reference)
//
#include <hip/hip_runtime.h>
#include <cfloat>

// Problem constants
#define B_SZ 8
#define N_SZ 2048
#define D_SZ 512
#define K_SZ 8192
#define M_SZ (B_SZ * N_SZ)  // 16384

#define DECAY_F 0.99f
#define OMD_F ((float)(1.0 - 0.99))  // one-minus-decay, rounded to f32
#define EPS_F 1e-5f

// Output layout (flat float offsets, reference return order)
#define OUT1_OFF 8388608   // indices (B*N) as float
#define OUT2_OFF 8404992   // commitment loss (1)
#define OUT3_OFF 8404993   // new_ema_cluster_sizes (K)
#define OUT4_OFF 8413185   // new_ema_codebook (K*D)
#define OUT5_OFF 12607489  // new_embedding (K*D)

// Argmin-GEMM tiling
#define BM 128
#define BN 128
#define DKC 32
#define NSPLIT 8
#define KSPLIT (K_SZ / NSPLIT)  // 1024 cols per block
#define CT (KSPLIT / BN)        // 8 col-tiles per block

// ---------------- e_sq: per-codebook-row squared norm ----------------
__global__ __launch_bounds__(256) void k_esq(const float* __restrict__ e,
                                             float* __restrict__ esq) {
    int row = blockIdx.x * 4 + (threadIdx.x >> 6);
    int lane = threadIdx.x & 63;
    const float4* er = (const float4*)(e + (size_t)row * D_SZ);
    float s = 0.f;
#pragma unroll
    for (int i = 0; i < 2; ++i) {
        float4 v = er[lane + i * 64];
        s += v.x * v.x + v.y * v.y + v.z * v.z + v.w * v.w;
    }
#pragma unroll
    for (int off = 32; off; off >>= 1) s += __shfl_down(s, off);
    if (lane == 0) esq[row] = s;
}

// ---------------- init: out4 = 0.99*codebook, out3 = 0.99*sizes ------
__global__ __launch_bounds__(256) void k_init(const float* __restrict__ cb,
                                              const float* __restrict__ sizes,
                                              float* __restrict__ out3,
                                              float* __restrict__ out4) {
    int i = blockIdx.x * 256 + threadIdx.x;  // grid covers K*D exactly
    out4[i] = cb[i] * DECAY_F;
    if (i < K_SZ) out3[i] = sizes[i] * DECAY_F;
}

// ---------------- copy: quantized_ste == encoded_latents -------------
__global__ __launch_bounds__(256) void k_copy(const float* __restrict__ z,
                                              float* __restrict__ out0) {
    int i = blockIdx.x * 256 + threadIdx.x;  // grid covers M*D/4 exactly
    ((float4*)out0)[i] = ((const float4*)z)[i];
}

// ---------------- argmin distance GEMM -------------------------------
// grid = (M/BM, NSPLIT); block = 256 threads; 8x8 accumulators/thread.
__global__ __launch_bounds__(256) void k_argmin(const float* __restrict__ z,
                                                const float* __restrict__ e,
                                                const float* __restrict__ esq,
                                                float* __restrict__ candB,
                                                int* __restrict__ candI) {
    __shared__ float zs[DKC][BM + 4];
    __shared__ float es[DKC][BN + 4];

    const int tid = threadIdx.x;
    const int ty = tid >> 4;   // 0..15 -> 8 rows each
    const int tx = tid & 15;   // 0..15 -> 8 cols each
    const int row0 = blockIdx.x * BM;
    const int cbase = blockIdx.y * KSPLIT;

    float best[8];
    int bidx[8];
#pragma unroll
    for (int m = 0; m < 8; ++m) { best[m] = FLT_MAX; bidx[m] = 0; }

    for (int ct = 0; ct < CT; ++ct) {
        const int col0 = cbase + ct * BN;
        float acc[8][8];
#pragma unroll
        for (int m = 0; m < 8; ++m)
#pragma unroll
            for (int n = 0; n < 8; ++n) acc[m][n] = 0.f;

        for (int dk = 0; dk < D_SZ / DKC; ++dk) {
            const int d0 = dk * DKC;
            __syncthreads();
#pragma unroll
            for (int i = 0; i < 4; ++i) {
                int idx = tid + i * 256;      // 0..1023
                int m = idx >> 3;             // 0..127
                int k4 = idx & 7;             // 0..7
                float4 v = *(const float4*)(z + (size_t)(row0 + m) * D_SZ + d0 + k4 * 4);
                zs[k4 * 4 + 0][m] = v.x;
                zs[k4 * 4 + 1][m] = v.y;
                zs[k4 * 4 + 2][m] = v.z;
                zs[k4 * 4 + 3][m] = v.w;
                float4 w = *(const float4*)(e + (size_t)(col0 + m) * D_SZ + d0 + k4 * 4);
                es[k4 * 4 + 0][m] = w.x;
                es[k4 * 4 + 1][m] = w.y;
                es[k4 * 4 + 2][m] = w.z;
                es[k4 * 4 + 3][m] = w.w;
            }
            __syncthreads();
#pragma unroll
            for (int kk = 0; kk < DKC; ++kk) {
                float a[8], b[8];
#pragma unroll
                for (int m = 0; m < 8; ++m) a[m] = zs[kk][ty * 8 + m];
#pragma unroll
                for (int n = 0; n < 8; ++n) b[n] = es[kk][tx * 8 + n];
#pragma unroll
                for (int m = 0; m < 8; ++m)
#pragma unroll
                    for (int n = 0; n < 8; ++n)
                        acc[m][n] = fmaf(a[m], b[n], acc[m][n]);
            }
        }
        // epilogue: dist = e_sq - 2*dot (z_sq is row-constant, argmin-invariant)
#pragma unroll
        for (int n = 0; n < 8; ++n) {
            int col = col0 + tx * 8 + n;
            float eq = esq[col];
#pragma unroll
            for (int m = 0; m < 8; ++m) {
                float dist = fmaf(-2.0f, acc[m][n], eq);
                if (dist < best[m]) { best[m] = dist; bidx[m] = col; }
            }
        }
    }

    // reduce across the 16 tx lanes (same ty = 16 consecutive lanes in a wave)
#pragma unroll
    for (int off = 1; off < 16; off <<= 1) {
#pragma unroll
        for (int m = 0; m < 8; ++m) {
            float ob = __shfl_xor(best[m], off);
            int oi = __shfl_xor(bidx[m], off);
            if (ob < best[m] || (ob == best[m] && oi < bidx[m])) {
                best[m] = ob;
                bidx[m] = oi;
            }
        }
    }
    if (tx == 0) {
#pragma unroll
        for (int m = 0; m < 8; ++m) {
            int row = row0 + ty * 8 + m;
            candB[row * NSPLIT + blockIdx.y] = best[m];
            candI[row * NSPLIT + blockIdx.y] = bidx[m];
        }
    }
}

// ---------------- merge the NSPLIT candidates per row ----------------
__global__ __launch_bounds__(256) void k_merge(const float* __restrict__ candB,
                                               const int* __restrict__ candI,
                                               int* __restrict__ nearest,
                                               float* __restrict__ out1) {
    int row = blockIdx.x * 256 + threadIdx.x;  // grid covers M exactly
    float b = FLT_MAX;
    int bi = 0;
#pragma unroll
    for (int s = 0; s < NSPLIT; ++s) {
        float v = candB[row * NSPLIT + s];
        int i = candI[row * NSPLIT + s];
        if (v < b || (v == b && i < bi)) { b = v; bi = i; }
    }
    nearest[row] = bi;
    out1[row] = (float)bi;
}

// ---------------- scatter: EMA accumulate + commitment loss ----------
__global__ __launch_bounds__(256) void k_scatter(const float* __restrict__ z,
                                                 const float* __restrict__ e,
                                                 const int* __restrict__ nearest,
                                                 float* __restrict__ out3,
                                                 float* __restrict__ out4,
                                                 float* __restrict__ lossAcc) {
    const int tid = threadIdx.x;  // 256 threads, each handles 2 elems/row
    float lp = 0.f;
    const int base_row = blockIdx.x * 8;
#pragma unroll
    for (int r = 0; r < 8; ++r) {
        int row = base_row + r;
        int n = nearest[row];
        float2 zv = ((const float2*)(z + (size_t)row * D_SZ))[tid];
        float2 ev = ((const float2*)(e + (size_t)n * D_SZ))[tid];
        float* o4 = out4 + (size_t)n * D_SZ + tid * 2;
        atomicAdd(o4, OMD_F * zv.x);
        atomicAdd(o4 + 1, OMD_F * zv.y);
        float dx = zv.x - ev.x, dy = zv.y - ev.y;
        lp += dx * dx + dy * dy;
        if (tid == 0) atomicAdd(out3 + n, OMD_F);
    }
#pragma unroll
    for (int off = 32; off; off >>= 1) lp += __shfl_down(lp, off);
    __shared__ float red[4];
    if ((tid & 63) == 0) red[tid >> 6] = lp;
    __syncthreads();
    if (tid == 0) atomicAdd(lossAcc, red[0] + red[1] + red[2] + red[3]);
}

// ---------------- finalize: new_embedding + loss scalar --------------
__global__ __launch_bounds__(256) void k_final(const float* __restrict__ out3,
                                               const float* __restrict__ out4,
                                               float* __restrict__ out5,
                                               const float* __restrict__ lossAcc,
                                               float* __restrict__ out2) {
    int i = blockIdx.x * 256 + threadIdx.x;  // grid covers K*D exactly
    out5[i] = out4[i] / (out3[i >> 9] + EPS_F);
    if (i == 0) out2[0] = 0.25f * lossAcc[0] / 8388608.0f;
}

extern "C" void kernel_launch(void* const* d_in, const int* in_sizes, int n_in,
                              void* d_out, int out_size, void* d_ws, size_t ws_size,
                              hipStream_t stream) {
    const float* z = (const float*)d_in[0];      // encoded_latents (B*N, D)
    const float* ew = (const float*)d_in[1];     // embedding_weight (K, D)
    const float* sizes = (const float*)d_in[2];  // ema_cluster_sizes (K)
    const float* cb = (const float*)d_in[3];     // ema_codebook (K, D)

    float* out = (float*)d_out;
    float* out0 = out;             // quantized_ste == encoded_latents
    float* out1 = out + OUT1_OFF;  // indices (float)
    float* out2 = out + OUT2_OFF;  // loss
    float* out3 = out + OUT3_OFF;  // new_ema_cluster_sizes
    float* out4 = out + OUT4_OFF;  // new_ema_codebook
    float* out5 = out + OUT5_OFF;  // new_embedding

    // small scratch in ws
    int* nearest = (int*)d_ws;                      // 16384 ints
    float* esq = (float*)d_ws + M_SZ;               // 8192 floats
    float* lossAcc = (float*)d_ws + M_SZ + K_SZ;    // 1 float

    // argmin candidates staged in out5 (overwritten by k_final afterwards)
    float* candB = out5;                            // 16384*8 floats
    int* candI = (int*)(out5 + M_SZ * NSPLIT);      // 16384*8 ints

    hipMemsetAsync(lossAcc, 0, sizeof(float), stream);

    k_esq<<<K_SZ / 4, 256, 0, stream>>>(ew, esq);
    k_init<<<(K_SZ * D_SZ) / 256, 256, 0, stream>>>(cb, sizes, out3, out4);
    k_copy<<<(M_SZ * D_SZ / 4) / 256, 256, 0, stream>>>(z, out0);

    dim3 ag(M_SZ / BM, NSPLIT);
    k_argmin<<<ag, 256, 0, stream>>>(z, ew, esq, candB, candI);
    k_merge<<<M_SZ / 256, 256, 0, stream>>>(candB, candI, nearest, out1);
    k_scatter<<<M_SZ / 8, 256, 0, stream>>>(z, ew, nearest, out3, out4, lossAcc);
    k_final<<<(K_SZ * D_SZ) / 256, 256, 0, stream>>>(out3, out4, out5, lossAcc, out2);
}